// Round 12
// baseline (280.405 us; speedup 1.0000x reference)
//
#include <hip/hip_runtime.h>
#include <math.h>

// NetVLAD: B=8, N=2048, D=128, K=64, fp32 in/out.
#define BB 8
#define NN 2048
#define DD 128
#define KK 64
#define PP 64            // p-groups (512 blocks = 2/CU)
#define NPB (NN / PP)    // 32 descriptors per block
#define TI 16            // descriptors per half

// ---------------------------------------------------------------------------
// v12: TWO REGULAR DISPATCHES (coop launch condemned: v10/v11 both returned
// bit-identical absmax == max|ref| -> kernel never ran; launch silently
// rejected). k1 = v9's verified phase-1 body, but the epilogue atomicAdds
// the folded block contribution straight into vlad[B][K][D] (256 KB,
// pre-zeroed via hipMemsetAsync) — no 16 MB partial round-trip. k2 is a
// 256 KB-read normalize micro-kernel. Inter-kernel visibility = ordinary
// kernel-boundary coherence (same contract v9's plain stores used).
// ---------------------------------------------------------------------------
__global__ __launch_bounds__(512)
__attribute__((amdgpu_waves_per_eu(4, 4)))
void netvlad_k1(
    const float* __restrict__ x, const float* __restrict__ cent,
    float* __restrict__ vlad)
{
    const int b    = blockIdx.x >> 6;    // / PP
    const int p    = blockIdx.x & 63;    // % PP
    const int t    = threadIdx.x;
    const int h    = t >> 8;             // half 0/1
    const int u    = t & 255;            // index within half
    const int kq   = u >> 3;             // 0..31: owns k = {2kq, 2kq+1}
    const int pr   = u & 7;              // 0..7: owns d-range [pr*16, +16)
    const int dbase = pr * 16;
    const int wv   = u >> 6;             // wave-in-half 0..3

    __shared__ __align__(16) float xs[2][TI][DD];   // 16 KB normalized tiles
    __shared__ __align__(16) float sL[2][TI][4];    // softmax wave-partials
    __shared__ __align__(16) float comb[256][36];   // 36 KB combine
    __shared__ float sAc[32][2];                    // h0's sumA per kq

    // Rotated chunk offsets: slot jj -> chunk ((jj+pr)&3) (<=2-way alias).
    int off[4];
    #pragma unroll
    for (int jj = 0; jj < 4; ++jj) off[jj] = dbase + (((jj + pr) & 3) << 2);

    // ---- x loads: this half's tile, row i0 = u>>4. 16B/lane coalesced.
    const int i0 = u >> 4, tl = u & 15;
    const float* xr = x + ((size_t)b * NN + (size_t)p * NPB + h * TI + i0) * DD;
    float4 v0 = *(const float4*)(xr + tl * 4);
    float4 v1 = *(const float4*)(xr + 64 + tl * 4);

    // ---- centroid fragments + ||c_k||^2 (overlap x loads; die after B)
    float4 cA[4], cB[4];
    float cn2a = 0.f, cn2b = 0.f;
    #pragma unroll
    for (int jj = 0; jj < 4; ++jj) {
        cA[jj] = *(const float4*)(cent + (2 * kq) * DD + off[jj]);
        cB[jj] = *(const float4*)(cent + (2 * kq + 1) * DD + off[jj]);
        cn2a += cA[jj].x*cA[jj].x + cA[jj].y*cA[jj].y + cA[jj].z*cA[jj].z + cA[jj].w*cA[jj].w;
        cn2b += cB[jj].x*cB[jj].x + cB[jj].y*cB[jj].y + cB[jj].z*cB[jj].z + cB[jj].w*cB[jj].w;
    }
    #pragma unroll
    for (int m = 1; m < 8; m <<= 1) {
        cn2a += __shfl_xor(cn2a, m);
        cn2b += __shfl_xor(cn2b, m);
    }

    // ---- normalize row i0 in registers, write xs[h] once
    {
        float ss = v0.x*v0.x + v0.y*v0.y + v0.z*v0.z + v0.w*v0.w
                 + v1.x*v1.x + v1.y*v1.y + v1.z*v1.z + v1.w*v1.w;
        #pragma unroll
        for (int m = 1; m < 16; m <<= 1) ss += __shfl_xor(ss, m);
        const float rn = 1.0f / fmaxf(sqrtf(ss), 1e-12f);
        v0.x *= rn; v0.y *= rn; v0.z *= rn; v0.w *= rn;
        v1.x *= rn; v1.y *= rn; v1.z *= rn; v1.w *= rn;
        *(float4*)(&xs[h][i0][tl * 4])      = v0;
        *(float4*)(&xs[h][i0][64 + tl * 4]) = v1;
    }
    __syncthreads();   // bar 1

    // ---- Phase B: dots + exp (e in regs). assign ∝ exp(||c||^2 - 2 xn·c)
    float e0[TI], e1[TI];
    #pragma unroll
    for (int i = 0; i < TI; ++i) {
        float S0 = 0.f, S1 = 0.f;
        #pragma unroll
        for (int jj = 0; jj < 4; ++jj) {
            float4 v = *(const float4*)(&xs[h][i][off[jj]]);
            S0 += v.x*cA[jj].x + v.y*cA[jj].y + v.z*cA[jj].z + v.w*cA[jj].w;
            S1 += v.x*cB[jj].x + v.y*cB[jj].y + v.z*cB[jj].z + v.w*cB[jj].w;
        }
        #pragma unroll
        for (int m = 1; m < 8; m <<= 1) {   // reduce across the 8 d-parts
            S0 += __shfl_xor(S0, m);
            S1 += __shfl_xor(S1, m);
        }
        e0[i] = __expf(cn2a - 2.f * S0);
        e1[i] = __expf(cn2b - 2.f * S1);
        float es = e0[i] + e1[i];
        #pragma unroll
        for (int m = 8; m < 64; m <<= 1) es += __shfl_xor(es, m);
        if ((u & 63) == 0) sL[h][i][wv] = es;
    }
    __syncthreads();   // bar 2 (cA/cB dead from here)

    // ---- Phase C: accumulate assign * xn
    float4 acc0[4], acc1[4];
    #pragma unroll
    for (int jj = 0; jj < 4; ++jj) {
        acc0[jj] = make_float4(0.f, 0.f, 0.f, 0.f);
        acc1[jj] = make_float4(0.f, 0.f, 0.f, 0.f);
    }
    float sA0 = 0.f, sA1 = 0.f;
    #pragma unroll
    for (int i = 0; i < TI; ++i) {
        const float4 s4 = *(const float4*)(&sL[h][i][0]);   // broadcast
        const float rs = 1.0f / (s4.x + s4.y + s4.z + s4.w);
        const float a0 = e0[i] * rs, a1 = e1[i] * rs;
        sA0 += a0; sA1 += a1;
        #pragma unroll
        for (int jj = 0; jj < 4; ++jj) {
            float4 v = *(const float4*)(&xs[h][i][off[jj]]);
            acc0[jj].x += a0*v.x; acc0[jj].y += a0*v.y; acc0[jj].z += a0*v.z; acc0[jj].w += a0*v.w;
            acc1[jj].x += a1*v.x; acc1[jj].y += a1*v.y; acc1[jj].z += a1*v.z; acc1[jj].w += a1*v.w;
        }
    }

    // ---- combine halves: h0 stages; h1 adds, folds -sumA*c (cent L2-hot),
    // and atomicAdds into the 256 KB vlad accumulator (L2/LLC-resident).
    if (h == 0) {
        #pragma unroll
        for (int jj = 0; jj < 4; ++jj) {
            *(float4*)(&comb[u][jj * 4])      = acc0[jj];
            *(float4*)(&comb[u][16 + jj * 4]) = acc1[jj];
        }
        if (pr == 0) { sAc[kq][0] = sA0; sAc[kq][1] = sA1; }
    }
    __syncthreads();   // bar 3

    if (h == 1) {
        sA0 += sAc[kq][0];
        sA1 += sAc[kq][1];
        #pragma unroll
        for (int jj = 0; jj < 4; ++jj) {
            const float4 c0 = *(const float4*)(cent + (2 * kq) * DD + off[jj]);
            const float4 c1 = *(const float4*)(cent + (2 * kq + 1) * DD + off[jj]);
            const float4 o0 = *(const float4*)(&comb[u][jj * 4]);
            const float4 o1 = *(const float4*)(&comb[u][16 + jj * 4]);
            float4 r0 = acc0[jj], r1 = acc1[jj];
            r0.x += o0.x; r0.y += o0.y; r0.z += o0.z; r0.w += o0.w;
            r1.x += o1.x; r1.y += o1.y; r1.z += o1.z; r1.w += o1.w;
            r0.x -= sA0 * c0.x; r0.y -= sA0 * c0.y;
            r0.z -= sA0 * c0.z; r0.w -= sA0 * c0.w;
            r1.x -= sA1 * c1.x; r1.y -= sA1 * c1.y;
            r1.z -= sA1 * c1.z; r1.w -= sA1 * c1.w;
            float* p0 = vlad + ((size_t)(b * KK) + 2 * kq)     * DD + off[jj];
            float* p1 = vlad + ((size_t)(b * KK) + 2 * kq + 1) * DD + off[jj];
            atomicAdd(p0 + 0, r0.x); atomicAdd(p0 + 1, r0.y);
            atomicAdd(p0 + 2, r0.z); atomicAdd(p0 + 3, r0.w);
            atomicAdd(p1 + 0, r1.x); atomicAdd(p1 + 1, r1.y);
            atomicAdd(p1 + 2, r1.z); atomicAdd(p1 + 3, r1.w);
        }
    }
}

// ---------------------------------------------------------------------------
// K2 v12: normalize micro-kernel. 512 blocks (one per (b,k)) x 64 threads;
// lanes 0..31 read the 128-float row (L2-hot, 256 KB total), 32-lane
// shuffle-reduce, intra-norm + global factor (sqrt(K)=8 -> 0.125).
// ---------------------------------------------------------------------------
__global__ __launch_bounds__(64) void netvlad_k2(
    const float* __restrict__ vlad, float* __restrict__ out)
{
    const int b = blockIdx.x >> 6;
    const int k = blockIdx.x & 63;
    const int t = threadIdx.x;
    if (t < 32) {
        const float4 v0 = *(const float4*)(vlad + ((size_t)(b * KK) + k) * DD + t * 4);
        float4 v = v0;
        float ss = v.x*v.x + v.y*v.y + v.z*v.z + v.w*v.w;
        #pragma unroll
        for (int m = 1; m < 32; m <<= 1) ss += __shfl_xor(ss, m);
        const float rn = 0.125f / fmaxf(sqrtf(ss), 1e-12f);
        v.x *= rn; v.y *= rn; v.z *= rn; v.w *= rn;
        *(float4*)(out + ((size_t)b * KK + k) * DD + t * 4) = v;
    }
}

extern "C" void kernel_launch(void* const* d_in, const int* in_sizes, int n_in,
                              void* d_out, int out_size, void* d_ws, size_t ws_size,
                              hipStream_t stream) {
    const float* x    = (const float*)d_in[0];   // [8, 2048, 128] fp32
    const float* cent = (const float*)d_in[1];   // [64, 128] fp32
    float* out = (float*)d_out;                  // [8, 8192] fp32

    float* vlad = (float*)d_ws;                  // 8*64*128 fp32 = 256 KB

    hipMemsetAsync(d_ws, 0, (size_t)BB * KK * DD * 4, stream);   // zero accumulator
    netvlad_k1<<<dim3(BB * PP), dim3(512), 0, stream>>>(x, cent, vlad);
    netvlad_k2<<<dim3(BB * KK), dim3(64), 0, stream>>>(vlad, out);
}

// Round 13
// 87.823 us; speedup vs baseline: 3.1928x; 3.1928x over previous
//
#include <hip/hip_runtime.h>
#include <math.h>

// NetVLAD: B=8, N=2048, D=128, K=64, fp32 in/out.
#define BB 8
#define NN 2048
#define DD 128
#define KK 64
#define PP 64            // partial groups per batch (512 blocks = 2/CU)
#define NPB (NN / PP)    // 32 descriptors per block
#define TI 16            // descriptors per half

// ---------------------------------------------------------------------------
// K1 (v9, best verified: 87.1 µs total): two 256-thread halves, LDS combine,
// ONE 16 MB partial set; cA/cB die after Phase B; h==1 epilogue re-loads
// cent (L2-hot) for the -sumA*c fold (no-spill liveness, v7-proven).
// Condemned alternatives (measured): coop fusion (v10/v11: silent launch
// no-op), atomicAdd accumulation (v12: 4.2M RMWs -> 148 MB writebacks,
// 225 µs), PP=128 single-tile (more partial traffic), 64-VGPR targets
// (spill: +90 MB scratch traffic).
//   bar1: xs[h] tiles normalized/visible
//   bar2: sL[h] softmax partials
//   (Phase C in regs)
//   bar3: h0's acc + sumA staged in LDS -> h1 adds, folds, writes.
// ---------------------------------------------------------------------------
__global__ __launch_bounds__(512)
__attribute__((amdgpu_waves_per_eu(4, 4)))
void netvlad_k1(
    const float* __restrict__ x, const float* __restrict__ cent,
    float* __restrict__ part_acc)
{
    const int b    = blockIdx.x >> 6;    // / PP
    const int p    = blockIdx.x & 63;    // % PP
    const int t    = threadIdx.x;
    const int h    = t >> 8;             // half 0/1
    const int u    = t & 255;            // index within half
    const int kq   = u >> 3;             // 0..31: owns k = {2kq, 2kq+1}
    const int pr   = u & 7;              // 0..7: owns d-range [pr*16, +16)
    const int dbase = pr * 16;
    const int wv   = u >> 6;             // wave-in-half 0..3

    __shared__ __align__(16) float xs[2][TI][DD];   // 16 KB normalized tiles
    __shared__ __align__(16) float sL[2][TI][4];    // softmax wave-partials
    __shared__ __align__(16) float comb[256][36];   // 36 KB combine
    __shared__ float sAc[32][2];                    // h0's sumA per kq

    // Rotated chunk offsets: slot jj -> chunk ((jj+pr)&3) (<=2-way alias).
    int off[4];
    #pragma unroll
    for (int jj = 0; jj < 4; ++jj) off[jj] = dbase + (((jj + pr) & 3) << 2);

    // ---- x loads: this half's tile, row i0 = u>>4. 16B/lane coalesced.
    const int i0 = u >> 4, tl = u & 15;
    const float* xr = x + ((size_t)b * NN + (size_t)p * NPB + h * TI + i0) * DD;
    float4 v0 = *(const float4*)(xr + tl * 4);
    float4 v1 = *(const float4*)(xr + 64 + tl * 4);

    // ---- centroid fragments + ||c_k||^2 (overlaps x loads; die after B)
    float4 cA[4], cB[4];
    float cn2a = 0.f, cn2b = 0.f;
    #pragma unroll
    for (int jj = 0; jj < 4; ++jj) {
        cA[jj] = *(const float4*)(cent + (2 * kq) * DD + off[jj]);
        cB[jj] = *(const float4*)(cent + (2 * kq + 1) * DD + off[jj]);
        cn2a += cA[jj].x*cA[jj].x + cA[jj].y*cA[jj].y + cA[jj].z*cA[jj].z + cA[jj].w*cA[jj].w;
        cn2b += cB[jj].x*cB[jj].x + cB[jj].y*cB[jj].y + cB[jj].z*cB[jj].z + cB[jj].w*cB[jj].w;
    }
    #pragma unroll
    for (int m = 1; m < 8; m <<= 1) {
        cn2a += __shfl_xor(cn2a, m);
        cn2b += __shfl_xor(cn2b, m);
    }

    // ---- normalize row i0 in registers (16-lane groups), write xs[h] once
    {
        float ss = v0.x*v0.x + v0.y*v0.y + v0.z*v0.z + v0.w*v0.w
                 + v1.x*v1.x + v1.y*v1.y + v1.z*v1.z + v1.w*v1.w;
        #pragma unroll
        for (int m = 1; m < 16; m <<= 1) ss += __shfl_xor(ss, m);
        const float rn = 1.0f / fmaxf(sqrtf(ss), 1e-12f);
        v0.x *= rn; v0.y *= rn; v0.z *= rn; v0.w *= rn;
        v1.x *= rn; v1.y *= rn; v1.z *= rn; v1.w *= rn;
        *(float4*)(&xs[h][i0][tl * 4])      = v0;
        *(float4*)(&xs[h][i0][64 + tl * 4]) = v1;
    }
    __syncthreads();   // bar 1

    // ---- Phase B: dots + exp (e in registers). assign ∝ exp(||c||^2 - 2 xn·c)
    float e0[TI], e1[TI];
    #pragma unroll
    for (int i = 0; i < TI; ++i) {
        float S0 = 0.f, S1 = 0.f;
        #pragma unroll
        for (int jj = 0; jj < 4; ++jj) {
            float4 v = *(const float4*)(&xs[h][i][off[jj]]);
            S0 += v.x*cA[jj].x + v.y*cA[jj].y + v.z*cA[jj].z + v.w*cA[jj].w;
            S1 += v.x*cB[jj].x + v.y*cB[jj].y + v.z*cB[jj].z + v.w*cB[jj].w;
        }
        #pragma unroll
        for (int m = 1; m < 8; m <<= 1) {   // reduce across the 8 d-parts
            S0 += __shfl_xor(S0, m);
            S1 += __shfl_xor(S1, m);
        }
        e0[i] = __expf(cn2a - 2.f * S0);
        e1[i] = __expf(cn2b - 2.f * S1);
        float es = e0[i] + e1[i];
        #pragma unroll
        for (int m = 8; m < 64; m <<= 1) es += __shfl_xor(es, m);
        if ((u & 63) == 0) sL[h][i][wv] = es;
    }
    __syncthreads();   // bar 2 (cA/cB dead from here)

    // ---- Phase C: accumulate assign * xn
    float4 acc0[4], acc1[4];
    #pragma unroll
    for (int jj = 0; jj < 4; ++jj) {
        acc0[jj] = make_float4(0.f, 0.f, 0.f, 0.f);
        acc1[jj] = make_float4(0.f, 0.f, 0.f, 0.f);
    }
    float sA0 = 0.f, sA1 = 0.f;
    #pragma unroll
    for (int i = 0; i < TI; ++i) {
        const float4 s4 = *(const float4*)(&sL[h][i][0]);   // broadcast
        const float rs = 1.0f / (s4.x + s4.y + s4.z + s4.w);
        const float a0 = e0[i] * rs, a1 = e1[i] * rs;
        sA0 += a0; sA1 += a1;
        #pragma unroll
        for (int jj = 0; jj < 4; ++jj) {
            float4 v = *(const float4*)(&xs[h][i][off[jj]]);
            acc0[jj].x += a0*v.x; acc0[jj].y += a0*v.y; acc0[jj].z += a0*v.z; acc0[jj].w += a0*v.w;
            acc1[jj].x += a1*v.x; acc1[jj].y += a1*v.y; acc1[jj].z += a1*v.z; acc1[jj].w += a1*v.w;
        }
    }

    // ---- combine halves: h0 stages, h1 adds + folds (cent re-loaded,
    // L2-hot) + writes. v7-proven liveness pattern.
    if (h == 0) {
        #pragma unroll
        for (int jj = 0; jj < 4; ++jj) {
            *(float4*)(&comb[u][jj * 4])      = acc0[jj];
            *(float4*)(&comb[u][16 + jj * 4]) = acc1[jj];
        }
        if (pr == 0) { sAc[kq][0] = sA0; sAc[kq][1] = sA1; }
    }
    __syncthreads();   // bar 3: h0's accumulators visible

    if (h == 1) {
        sA0 += sAc[kq][0];
        sA1 += sAc[kq][1];
        const size_t base = (size_t)(b * PP + p) * KK * DD;
        #pragma unroll
        for (int jj = 0; jj < 4; ++jj) {
            const float4 c0 = *(const float4*)(cent + (2 * kq) * DD + off[jj]);
            const float4 c1 = *(const float4*)(cent + (2 * kq + 1) * DD + off[jj]);
            const float4 o0 = *(const float4*)(&comb[u][jj * 4]);
            const float4 o1 = *(const float4*)(&comb[u][16 + jj * 4]);
            float4 r0 = acc0[jj], r1 = acc1[jj];
            r0.x += o0.x; r0.y += o0.y; r0.z += o0.z; r0.w += o0.w;
            r1.x += o1.x; r1.y += o1.y; r1.z += o1.z; r1.w += o1.w;
            r0.x -= sA0 * c0.x; r0.y -= sA0 * c0.y;
            r0.z -= sA0 * c0.z; r0.w -= sA0 * c0.w;
            r1.x -= sA1 * c1.x; r1.y -= sA1 * c1.y;
            r1.z -= sA1 * c1.z; r1.w -= sA1 * c1.w;
            *(float4*)(part_acc + base + (2 * kq) * DD + off[jj])     = r0;
            *(float4*)(part_acc + base + (2 * kq + 1) * DD + off[jj]) = r1;
        }
    }
}

// ---------------------------------------------------------------------------
// K2 (v9): sum 64 partials per (b,k) (4-deep independent chains, 512
// threads), intra-normalize, apply global factor (sqrt(K)=8 -> 0.125;
// -sumA*c already folded in K1). Grid: BB*KK = 512 blocks.
// ---------------------------------------------------------------------------
__global__ __launch_bounds__(512) void netvlad_k2(
    const float* __restrict__ part_acc, float* __restrict__ out)
{
    const int b  = blockIdx.x >> 6;
    const int k  = blockIdx.x & 63;
    const int t  = threadIdx.x;
    const int d4 = t & 31;               // float4 column 0..31
    const int ps = t >> 5;               // p-slice 0..15

    float4 acc = make_float4(0.f, 0.f, 0.f, 0.f);
    const float* base = part_acc + ((size_t)(b * PP) * KK + k) * DD + d4 * 4;
    #pragma unroll
    for (int j = 0; j < 4; ++j) {        // p = j*16 + ps
        const float4 v = *(const float4*)(base + (size_t)(j * 16 + ps) * KK * DD);
        acc.x += v.x; acc.y += v.y; acc.z += v.z; acc.w += v.w;
    }

    __shared__ __align__(16) float4 red[16][32];
    red[ps][d4] = acc;
    __syncthreads();

    if (t < 32) {
        float4 v = red[0][t];
        #pragma unroll
        for (int s = 1; s < 16; ++s) {
            v.x += red[s][t].x; v.y += red[s][t].y;
            v.z += red[s][t].z; v.w += red[s][t].w;
        }
        float ss = v.x*v.x + v.y*v.y + v.z*v.z + v.w*v.w;
        #pragma unroll
        for (int m = 1; m < 32; m <<= 1) ss += __shfl_xor(ss, m);
        const float rn = 0.125f / fmaxf(sqrtf(ss), 1e-12f);
        v.x *= rn; v.y *= rn; v.z *= rn; v.w *= rn;
        *(float4*)(out + ((size_t)b * KK + k) * DD + t * 4) = v;
    }
}

extern "C" void kernel_launch(void* const* d_in, const int* in_sizes, int n_in,
                              void* d_out, int out_size, void* d_ws, size_t ws_size,
                              hipStream_t stream) {
    const float* x    = (const float*)d_in[0];   // [8, 2048, 128] fp32
    const float* cent = (const float*)d_in[1];   // [64, 128] fp32
    float* out = (float*)d_out;                  // [8, 8192] fp32

    float* part_acc = (float*)d_ws;              // 8*64*64*128 fp32 = 16 MB

    netvlad_k1<<<dim3(BB * PP), dim3(512), 0, stream>>>(x, cent, part_acc);
    netvlad_k2<<<dim3(BB * KK), dim3(512), 0, stream>>>(part_acc, out);
}